// Round 2
// baseline (329.991 us; speedup 1.0000x reference)
//
#include <hip/hip_runtime.h>
#include <hip/hip_bf16.h>
#include <math.h>

// B=4, S=2048, D=1024, H=16, DK=64. fp32 I/O. bf16 MFMA internals.

#define B_SZ   4
#define S_LEN  2048
#define D_DIM  1024
#define NH     16
#define DKD    64
#define M_TOT  (B_SZ * S_LEN)   // 8192

typedef __bf16 bf16_t;
typedef bf16_t bf16x8 __attribute__((ext_vector_type(8)));
typedef bf16_t bf16x4 __attribute__((ext_vector_type(4)));
typedef float  f32x4  __attribute__((ext_vector_type(4)));

typedef __attribute__((address_space(1))) void gvoid;
typedef __attribute__((address_space(3))) void lvoid;

extern "C" __device__ float __ocml_native_exp2_f32(float);  // single v_exp_f32

// ---------------------------------------------------------------------------
// fp32 -> bf16 convert. cvt3: three weight matrices in one launch (z selects).
// ---------------------------------------------------------------------------
__global__ __launch_bounds__(256)
void cvt3_kernel(const float* __restrict__ s0, const float* __restrict__ s1,
                 const float* __restrict__ s2, bf16_t* __restrict__ d0,
                 bf16_t* __restrict__ d1, bf16_t* __restrict__ d2, int n4)
{
    const float* src = (blockIdx.z == 0) ? s0 : (blockIdx.z == 1) ? s1 : s2;
    bf16_t*      dst = (blockIdx.z == 0) ? d0 : (blockIdx.z == 1) ? d1 : d2;
    const int i = blockIdx.x * blockDim.x + threadIdx.x;
    if (i < n4) {
        f32x4 v = *(const f32x4*)(src + (size_t)i * 4);
        bf16x4 o;
        #pragma unroll
        for (int j = 0; j < 4; ++j) o[j] = (bf16_t)v[j];
        *(bf16x4*)(dst + (size_t)i * 4) = o;
    }
}

__global__ __launch_bounds__(256)
void cvt_kernel(const float* __restrict__ src, bf16_t* __restrict__ dst, int n4)
{
    const int i = blockIdx.x * blockDim.x + threadIdx.x;
    if (i < n4) {
        f32x4 v = *(const f32x4*)(src + (size_t)i * 4);
        bf16x4 o;
        #pragma unroll
        for (int j = 0; j < 4; ++j) o[j] = (bf16_t)v[j];
        *(bf16x4*)(dst + (size_t)i * 4) = o;
    }
}

// ---------------------------------------------------------------------------
// Fused QKV projection GEMM, grid (64, 8, 3). BM=BN=128, BK=64 as two 32-wide
// sub-tiles (m97 LDS geometry preserved). A fp32: reg-prefetch + cvt +
// ds_write; W bf16: global_load_lds width=16. z==2 writes transposed (Vt).
// ---------------------------------------------------------------------------
__global__ __launch_bounds__(256, 2)
void qkv_gemm(const float* __restrict__ Aq, const float* __restrict__ Ak,
              const float* __restrict__ Av,
              const bf16_t* __restrict__ Wqb, const bf16_t* __restrict__ Wkb,
              const bf16_t* __restrict__ Wvb,
              const float* __restrict__ bq, const float* __restrict__ bk,
              const float* __restrict__ bv,
              bf16_t* __restrict__ Qw, bf16_t* __restrict__ Kw,
              bf16_t* __restrict__ Vt, float qscale)
{
    constexpr int K = 1024, N = 1024;
    constexpr int BM = 128, BK = 64;

    __shared__ __align__(16) bf16_t lA[2][BM * 32];   // 16 KB
    __shared__ __align__(16) bf16_t lB[2][128 * 32];  // 16 KB

    const int z = blockIdx.z;
    const float* A  = (z == 0) ? Aq : (z == 1) ? Ak : Av;
    const bf16_t* W = (z == 0) ? Wqb : (z == 1) ? Wkb : Wvb;
    const float* bias = (z == 0) ? bq : (z == 1) ? bk : bv;
    const float scale = (z == 0) ? qscale : 1.0f;

    const int tid  = threadIdx.x;
    const int wave = tid >> 6;
    const int lane = tid & 63;

    const int row0 = blockIdx.x * BM;
    const int col0 = blockIdx.y * 128;

    const int wr = (wave >> 1) * 64;
    const int wc = (wave & 1) * 64;

    f32x4 acc[4][4] = {};

    const int frow = lane & 15;
    const int kq   = (lane >> 4) * 8;

    // A staging: full 128x64 tile; thread handles 4 chunks of 8 elems.
    const int arow = tid >> 3;          // + p*32
    const int ak8  = (tid & 7) * 8;     // k offset in tile
    const int asub = (tid >> 2) & 1;
    const int akk  = (tid & 3) * 8;

    f32x4 pa[4][2];
    #pragma unroll
    for (int p = 0; p < 4; ++p) {
        const float* g = A + (size_t)(row0 + p * 32 + arow) * K + ak8;
        pa[p][0] = *(const f32x4*)g;
        pa[p][1] = *(const f32x4*)(g + 4);
    }

    for (int k0 = 0; k0 < K; k0 += BK) {
        __syncthreads();
        #pragma unroll
        for (int p = 0; p < 4; ++p) {
            bf16x8 a8;
            #pragma unroll
            for (int j = 0; j < 4; ++j) {
                a8[j]     = (bf16_t)pa[p][0][j];
                a8[4 + j] = (bf16_t)pa[p][1][j];
            }
            *(bf16x8*)(&lA[asub][(p * 32 + arow) * 32 + akk]) = a8;
        }
        #pragma unroll
        for (int s = 0; s < 2; ++s)
            #pragma unroll
            for (int c = 0; c < 2; ++c) {
                const int chunk = c * 4 + wave;
                const int e     = chunk * 512 + lane * 8;
                const int rr    = e >> 5;
                const int kk    = e & 31;
                __builtin_amdgcn_global_load_lds(
                    (gvoid*)(W + (size_t)(col0 + rr) * K + k0 + 32 * s + kk),
                    (lvoid*)(&lB[s][chunk * 512]), 16, 0, 0);
            }
        __syncthreads();

        // prefetch next A tile (covers both sub-tile compute phases)
        if (k0 + BK < K) {
            #pragma unroll
            for (int p = 0; p < 4; ++p) {
                const float* g = A + (size_t)(row0 + p * 32 + arow) * K + (k0 + BK) + ak8;
                pa[p][0] = *(const f32x4*)g;
                pa[p][1] = *(const f32x4*)(g + 4);
            }
        }

        #pragma unroll
        for (int s = 0; s < 2; ++s) {
            bf16x8 af[4], bfr[4];
            #pragma unroll
            for (int i = 0; i < 4; ++i) {
                af[i]  = *(const bf16x8*)(&lA[s][(wr + i * 16 + frow) * 32 + kq]);
                bfr[i] = *(const bf16x8*)(&lB[s][(wc + i * 16 + frow) * 32 + kq]);
            }
            #pragma unroll
            for (int i = 0; i < 4; ++i)
                #pragma unroll
                for (int j = 0; j < 4; ++j)
                    acc[i][j] = __builtin_amdgcn_mfma_f32_16x16x32_bf16(af[i], bfr[j], acc[i][j], 0, 0, 0);
        }
    }

    // C/D layout: col=lane&15, row=(lane>>4)*4+reg  [m89/m91-verified]
    const int rb   = (lane >> 4) * 4;
    const int ccol = lane & 15;
    #pragma unroll
    for (int j = 0; j < 4; ++j) {
        const int n = col0 + wc + j * 16 + ccol;
        const float bvv = bias[n];
        #pragma unroll
        for (int i = 0; i < 4; ++i) {
            const int m = row0 + wr + i * 16 + rb;
            if (z == 2) {
                bf16x4 o4;
                #pragma unroll
                for (int r = 0; r < 4; ++r) o4[r] = (bf16_t)(acc[i][j][r] + bvv);
                *(bf16x4*)(Vt + (size_t)n * M_TOT + m) = o4;   // V^T[n][m]
            } else {
                bf16_t* Cp = (z == 0) ? Qw : Kw;
                #pragma unroll
                for (int r = 0; r < 4; ++r)
                    Cp[(size_t)(m + r) * N + n] = (bf16_t)((acc[i][j][r] + bvv) * scale);
            }
        }
    }
}

// ---------------------------------------------------------------------------
// Out-projection GEMM: out_f32 = ctx_bf16 @ Wo_bf16^T + bo. BK=64 dual sub-tile.
// ---------------------------------------------------------------------------
__global__ __launch_bounds__(256, 2)
void gemm_out(const bf16_t* __restrict__ A, const bf16_t* __restrict__ Bt,
              const float* __restrict__ bias, float* __restrict__ C)
{
    constexpr int K = 1024, N = 1024;
    constexpr int BM = 128, BK = 64;

    __shared__ __align__(16) bf16_t lA[2][BM * 32];
    __shared__ __align__(16) bf16_t lB[2][128 * 32];

    const int tid  = threadIdx.x;
    const int wave = tid >> 6;
    const int lane = tid & 63;

    const int row0 = blockIdx.x * BM;
    const int col0 = blockIdx.y * 128;

    const int wr = (wave >> 1) * 64;
    const int wc = (wave & 1) * 64;

    f32x4 acc[4][4] = {};

    const int frow = lane & 15;
    const int kq   = (lane >> 4) * 8;

    for (int k0 = 0; k0 < K; k0 += BK) {
        __syncthreads();
        #pragma unroll
        for (int s = 0; s < 2; ++s)
            #pragma unroll
            for (int c = 0; c < 2; ++c) {
                const int chunk = c * 4 + wave;
                const int e     = chunk * 512 + lane * 8;
                const int r     = e >> 5;
                const int kk    = e & 31;
                __builtin_amdgcn_global_load_lds(
                    (gvoid*)(A + (size_t)(row0 + r) * K + k0 + 32 * s + kk),
                    (lvoid*)(&lA[s][chunk * 512]), 16, 0, 0);
                __builtin_amdgcn_global_load_lds(
                    (gvoid*)(Bt + (size_t)(col0 + r) * K + k0 + 32 * s + kk),
                    (lvoid*)(&lB[s][chunk * 512]), 16, 0, 0);
            }
        __syncthreads();

        #pragma unroll
        for (int s = 0; s < 2; ++s) {
            bf16x8 af[4], bfr[4];
            #pragma unroll
            for (int i = 0; i < 4; ++i) {
                af[i]  = *(const bf16x8*)(&lA[s][(wr + i * 16 + frow) * 32 + kq]);
                bfr[i] = *(const bf16x8*)(&lB[s][(wc + i * 16 + frow) * 32 + kq]);
            }
            #pragma unroll
            for (int i = 0; i < 4; ++i)
                #pragma unroll
                for (int j = 0; j < 4; ++j)
                    acc[i][j] = __builtin_amdgcn_mfma_f32_16x16x32_bf16(af[i], bfr[j], acc[i][j], 0, 0, 0);
        }
    }

    const int rb   = (lane >> 4) * 4;
    const int ccol = lane & 15;
    #pragma unroll
    for (int j = 0; j < 4; ++j) {
        const int n = col0 + wc + j * 16 + ccol;
        const float bvv = bias[n];
        #pragma unroll
        for (int i = 0; i < 4; ++i) {
            const int m = row0 + wr + i * 16 + rb;
            #pragma unroll
            for (int r = 0; r < 4; ++r)
                C[(size_t)(m + r) * N + n] = acc[i][j][r] + bvv;
        }
    }
}

// ---------------------------------------------------------------------------
// MFMA flash attention (no max-tracking; Q pre-scaled by 0.125*log2e).
// v2: 64 q-rows per wave (was 32) -> kf/vf LDS fragment reads amortized over
// 2x MFMAs; T14 async-stage (K/V global loads issued under previous tile's
// compute); T5 setprio around MFMA clusters.
// XCD swizzle: all 8 q-blocks of one (b,h) land on the same XCD so the
// K+V working set stays in its 4 MB L2 (blockIdx%8 = XCD heuristic).
// ---------------------------------------------------------------------------
__global__ __launch_bounds__(256, 2)
void attn_mfma(const bf16_t* __restrict__ Qg, const bf16_t* __restrict__ Kg,
               const bf16_t* __restrict__ Vt, bf16_t* __restrict__ ctx)
{
    constexpr int PSTR = 72;
    __shared__ __align__(16) bf16_t lK[64 * PSTR];        // 9 KB
    __shared__ __align__(16) bf16_t lV[64 * PSTR];        // 9 KB
    __shared__ __align__(16) bf16_t lP[4][64 * PSTR];     // 36 KB

    const int tid  = threadIdx.x;
    const int wave = tid >> 6;
    const int lane = tid & 63;
    const int qd   = lane >> 4;
    const int c    = lane & 15;

    // swizzle: g = j*64 + qblk*8 + xcd ; bh = j*8 + xcd (g mod 8 fixed per bh)
    const int g    = blockIdx.x;           // 0..511
    const int bh   = ((g >> 6) << 3) | (g & 7);
    const int qblk = (g >> 3) & 7;
    const int b    = bh >> 4;
    const int h    = bh & 15;

    const int q0 = qblk * 256 + wave * 64;

    const bf16_t* Qb = Qg + ((size_t)(b * S_LEN + q0)) * D_DIM + h * DKD;
    const bf16_t* Kb = Kg + ((size_t)(b * S_LEN)) * D_DIM + h * DKD;
    const bf16_t* Vb = Vt + ((size_t)(h * DKD)) * M_TOT + b * S_LEN;

    bf16_t* Pw = &lP[wave][0];

    bf16x8 qf[4][2];
    #pragma unroll
    for (int qt = 0; qt < 4; ++qt)
        #pragma unroll
        for (int ks = 0; ks < 2; ++ks)
            qf[qt][ks] = *(const bf16x8*)(Qb + (size_t)(qt * 16 + c) * D_DIM + ks * 32 + qd * 8);

    bf16x8 ones;
    #pragma unroll
    for (int i = 0; i < 8; ++i) ones[i] = (bf16_t)1.0f;

    f32x4 oacc[4][4] = {};
    f32x4 lacc[4]    = {};

    // staging: thread covers rows {srow, srow+32} x 16B chunk sc8
    const int srow = tid >> 3;
    const int sc8  = (tid & 7) * 8;

    // prologue prefetch (kt = 0)
    bf16x8 kv[2], vv[2];
    #pragma unroll
    for (int cc = 0; cc < 2; ++cc) {
        const int row = cc * 32 + srow;
        kv[cc] = *(const bf16x8*)(Kb + (size_t)row * D_DIM + sc8);
        vv[cc] = *(const bf16x8*)(Vb + (size_t)row * M_TOT + sc8);
    }

    for (int kt = 0; kt < S_LEN; kt += 64) {
        __syncthreads();
        #pragma unroll
        for (int cc = 0; cc < 2; ++cc) {
            const int row = cc * 32 + srow;
            *(bf16x8*)(lK + row * PSTR + sc8) = kv[cc];
            *(bf16x8*)(lV + row * PSTR + sc8) = vv[cc];
        }
        __syncthreads();

        // T14: issue next tile's global loads now; latency hides under compute
        if (kt + 64 < S_LEN) {
            #pragma unroll
            for (int cc = 0; cc < 2; ++cc) {
                const int row = cc * 32 + srow;
                kv[cc] = *(const bf16x8*)(Kb + (size_t)(kt + 64 + row) * D_DIM + sc8);
                vv[cc] = *(const bf16x8*)(Vb + (size_t)row * M_TOT + kt + 64 + sc8);
            }
        }

        bf16x8 kf[4][2];
        #pragma unroll
        for (int i = 0; i < 4; ++i)
            #pragma unroll
            for (int ks = 0; ks < 2; ++ks)
                kf[i][ks] = *(const bf16x8*)(lK + (i * 16 + c) * PSTR + ks * 32 + qd * 8);

        // QK^T + exp2 in two q-halves (caps live st registers at 32 VGPR)
        #pragma unroll
        for (int qh = 0; qh < 2; ++qh) {
            f32x4 st[4][2] = {};
            __builtin_amdgcn_s_setprio(1);
            #pragma unroll
            for (int ks = 0; ks < 2; ++ks)
                #pragma unroll
                for (int i = 0; i < 4; ++i)
                    #pragma unroll
                    for (int qt = 0; qt < 2; ++qt)
                        st[i][qt] = __builtin_amdgcn_mfma_f32_16x16x32_bf16(
                            kf[i][ks], qf[qh * 2 + qt][ks], st[i][qt], 0, 0, 0);
            __builtin_amdgcn_s_setprio(0);

            #pragma unroll
            for (int i = 0; i < 4; ++i)
                #pragma unroll
                for (int qt = 0; qt < 2; ++qt) {
                    bf16x4 pw;
                    #pragma unroll
                    for (int r = 0; r < 4; ++r)
                        pw[r] = (bf16_t)__ocml_native_exp2_f32(st[i][qt][r]);
                    *(bf16x4*)(Pw + ((qh * 2 + qt) * 16 + c) * PSTR + i * 16 + qd * 4) = pw;
                }
        }

        bf16x8 vf[4][2];
        #pragma unroll
        for (int fm = 0; fm < 4; ++fm)
            #pragma unroll
            for (int ks = 0; ks < 2; ++ks)
                vf[fm][ks] = *(const bf16x8*)(lV + (fm * 16 + c) * PSTR + ks * 32 + qd * 8);

        __builtin_amdgcn_s_setprio(1);
        #pragma unroll
        for (int qn = 0; qn < 4; ++qn)
            #pragma unroll
            for (int ks = 0; ks < 2; ++ks) {
                bf16x8 pf = *(const bf16x8*)(Pw + (qn * 16 + c) * PSTR + ks * 32 + qd * 8);
                lacc[qn] = __builtin_amdgcn_mfma_f32_16x16x32_bf16(ones, pf, lacc[qn], 0, 0, 0);
                #pragma unroll
                for (int fm = 0; fm < 4; ++fm)
                    oacc[fm][qn] = __builtin_amdgcn_mfma_f32_16x16x32_bf16(vf[fm][ks], pf, oacc[fm][qn], 0, 0, 0);
            }
        __builtin_amdgcn_s_setprio(0);
    }

    #pragma unroll
    for (int qn = 0; qn < 4; ++qn) {
        const float linv = 1.0f / lacc[qn][0];
        bf16_t* op = ctx + ((size_t)(b * S_LEN + q0 + qn * 16 + c)) * D_DIM + h * DKD + qd * 4;
        #pragma unroll
        for (int fm = 0; fm < 4; ++fm) {
            bf16x4 o4;
            #pragma unroll
            for (int r = 0; r < 4; ++r) o4[r] = (bf16_t)(oacc[fm][qn][r] * linv);
            *(bf16x4*)(op + fm * 16) = o4;
        }
    }
}

// ---------------------------------------------------------------------------
extern "C" void kernel_launch(void* const* d_in, const int* in_sizes, int n_in,
                              void* d_out, int out_size, void* d_ws, size_t ws_size,
                              hipStream_t stream)
{
    const float* query = (const float*)d_in[0];
    const float* key_  = (const float*)d_in[1];
    const float* value = (const float*)d_in[2];
    const float* Wq    = (const float*)d_in[3];
    const float* bq    = (const float*)d_in[4];
    const float* Wk    = (const float*)d_in[5];
    const float* bk    = (const float*)d_in[6];
    const float* Wv    = (const float*)d_in[7];
    const float* bv    = (const float*)d_in[8];
    const float* Wo    = (const float*)d_in[9];
    const float* bo    = (const float*)d_in[10];
    float* out = (float*)d_out;

    const size_t mat  = (size_t)M_TOT * D_DIM;
    const size_t wmat = (size_t)D_DIM * D_DIM;

    // ws (bf16), 66 MB: t0 16MB (Wk'/Wv' early; ctx later) | w0 2MB (Wq'->Wo')
    //                   | Qw 16MB | Kw 16MB | Vt 16MB
    bf16_t* t0 = (bf16_t*)d_ws;
    bf16_t* w0 = t0 + mat;
    bf16_t* Qw = w0 + wmat;
    bf16_t* Kw = Qw + mat;
    bf16_t* Vt = Kw + mat;
    bf16_t* w1 = t0;                 // Wk' (dead once qkv_gemm done)
    bf16_t* w2 = t0 + wmat;          // Wv'

    const int gcvt_w = (int)(wmat / 4 / 256);
    const float qscale = 0.18033688011112042f;   // 0.125 * log2(e)

    cvt3_kernel<<<dim3(gcvt_w, 1, 3), 256, 0, stream>>>(Wq, Wk, Wv, w0, w1, w2,
                                                        (int)(wmat / 4));

    qkv_gemm<<<dim3(M_TOT / 128, D_DIM / 128, 3), 256, 0, stream>>>(
        query, key_, value, w0, w1, w2, bq, bk, bv, Qw, Kw, Vt, qscale);

    cvt_kernel<<<gcvt_w, 256, 0, stream>>>(Wo, w0, (int)(wmat / 4));  // w0 free now

    attn_mfma<<<dim3(B_SZ * NH * (S_LEN / 256)), 256, 0, stream>>>(Qw, Kw, Vt, t0);

    gemm_out<<<dim3(M_TOT / 128, D_DIM / 128), 256, 0, stream>>>(t0, w0, bo, out);
}